// Round 1
// baseline (1047.528 us; speedup 1.0000x reference)
//
#include <hip/hip_runtime.h>
#include <hip/hip_bf16.h>
#include <math.h>

#define N_NODES 500000
#define DIM 256
#define ADIM 64
#define NG 512

// ---------------- prep: transpose W_att -> Wt_att[k][a], W_out -> Wt_out[d][o]
__global__ __launch_bounds__(256) void k_prep(const float* __restrict__ W_att,
                                              const float* __restrict__ W_out,
                                              float* __restrict__ Wt_att,
                                              float* __restrict__ Wt_out) {
    int idx = blockIdx.x * 256 + threadIdx.x;
    if (idx < ADIM * DIM) {
        int a = idx / DIM, k = idx % DIM;
        Wt_att[k * ADIM + a] = W_att[idx];
    }
    if (idx < DIM * DIM) {
        int o = idx / DIM, d = idx % DIM;
        Wt_out[d * DIM + o] = W_out[idx];
    }
}

// ---------------- segment offsets from sorted batch ids
__global__ __launch_bounds__(256) void k_offsets(const int* __restrict__ batch,
                                                 int* __restrict__ seg_start) {
    int i = blockIdx.x * 256 + threadIdx.x;
    if (i >= N_NODES) return;
    int b = batch[i];
    if (i == 0) {
        for (int g = 0; g <= b; g++) seg_start[g] = 0;
    } else {
        int pb = batch[i - 1];
        if (pb != b) {
            for (int g = pb + 1; g <= b; g++) seg_start[g] = i;
        }
    }
    if (i == N_NODES - 1) {
        for (int g = b + 1; g <= NG; g++) seg_start[g] = N_NODES;
    }
}

// ---------------- K1: scores[i] = ctx . tanh(W_att x_i + b_att)
// one thread per node; x tile (256 nodes x 32 k) staged in LDS with pad-33;
// Wt rows accessed at uniform addresses -> s_load, overlapped with FMAs.
__global__ __launch_bounds__(256) void k_scores(const float* __restrict__ x,
                                                const float* __restrict__ Wt,   // [DIM][ADIM]
                                                const float* __restrict__ b_att,
                                                const float* __restrict__ ctx,
                                                float* __restrict__ scores) {
    __shared__ float xs[256 * 33];
    const int t = threadIdx.x;
    const int base = blockIdx.x * 256;

    float acc[ADIM];
#pragma unroll
    for (int a = 0; a < ADIM; a++) acc[a] = 0.f;

    const int kr = (t & 7) * 4;        // k within chunk for staging
    const int rowbase = (t >> 3);      // node row within tile for staging

    for (int k0 = 0; k0 < DIM; k0 += 32) {
        __syncthreads();
#pragma unroll
        for (int p = 0; p < 8; p++) {
            int r = rowbase + p * 32;
            int node = base + r;
            float4 v = make_float4(0.f, 0.f, 0.f, 0.f);
            if (node < N_NODES)
                v = *(const float4*)(x + (size_t)node * DIM + k0 + kr);
            xs[r * 33 + kr + 0] = v.x;
            xs[r * 33 + kr + 1] = v.y;
            xs[r * 33 + kr + 2] = v.z;
            xs[r * 33 + kr + 3] = v.w;
        }
        __syncthreads();

#pragma unroll 4
        for (int k = 0; k < 32; k++) {
            float xv = xs[t * 33 + k];
            const float* wrow = Wt + (size_t)(k0 + k) * ADIM;  // uniform address
#pragma unroll
            for (int a = 0; a < ADIM; a++) acc[a] += xv * wrow[a];
        }
    }

    float s = 0.f;
#pragma unroll
    for (int a = 0; a < ADIM; a++) s += ctx[a] * tanhf(acc[a] + b_att[a]);

    int node = base + t;
    if (node < N_NODES) scores[node] = s;
}

// ---------------- K2: per-segment stable softmax -> w[i]
__global__ __launch_bounds__(256) void k_segsoftmax(const float* __restrict__ scores,
                                                    const int* __restrict__ seg_start,
                                                    float* __restrict__ w) {
    int g = blockIdx.x;
    int s0 = seg_start[g], s1 = seg_start[g + 1];
    int t = threadIdx.x;
    __shared__ float red[256];

    float m = -INFINITY;
    for (int i = s0 + t; i < s1; i += 256) m = fmaxf(m, scores[i]);
    red[t] = m;
    __syncthreads();
    for (int off = 128; off > 0; off >>= 1) {
        if (t < off) red[t] = fmaxf(red[t], red[t + off]);
        __syncthreads();
    }
    m = red[0];
    __syncthreads();

    float sum = 0.f;
    for (int i = s0 + t; i < s1; i += 256) sum += __expf(scores[i] - m);
    red[t] = sum;
    __syncthreads();
    for (int off = 128; off > 0; off >>= 1) {
        if (t < off) red[t] += red[t + off];
        __syncthreads();
    }
    float inv = 1.f / (red[0] + 1e-8f);

    for (int i = s0 + t; i < s1; i += 256) w[i] = __expf(scores[i] - m) * inv;
}

// ---------------- K3: pooled[g][d] = sum_i w_i * x[i][d]  (block per segment)
__global__ __launch_bounds__(256) void k_pool(const float* __restrict__ x,
                                              const float* __restrict__ w,
                                              const int* __restrict__ seg_start,
                                              float* __restrict__ pooled) {
    int g = blockIdx.x;
    int s0 = seg_start[g], s1 = seg_start[g + 1];
    int t = threadIdx.x;
    int c = (t & 63) * 4;       // 4 columns per thread; wave covers full 1KB row
    int grp = t >> 6;           // 0..3 : 4 nodes in flight per block

    float4 acc = make_float4(0.f, 0.f, 0.f, 0.f);
    for (int i = s0 + grp; i < s1; i += 4) {
        float wi = w[i];
        float4 v = *(const float4*)(x + (size_t)i * DIM + c);
        acc.x += wi * v.x;
        acc.y += wi * v.y;
        acc.z += wi * v.z;
        acc.w += wi * v.w;
    }

    __shared__ float4 red[4][64];
    red[grp][t & 63] = acc;
    __syncthreads();
    if (t < 64) {
        float4 r0 = red[0][t], r1 = red[1][t], r2 = red[2][t], r3 = red[3][t];
        float4 r;
        r.x = (r0.x + r1.x) + (r2.x + r3.x);
        r.y = (r0.y + r1.y) + (r2.y + r3.y);
        r.z = (r0.z + r1.z) + (r2.z + r3.z);
        r.w = (r0.w + r1.w) + (r2.w + r3.w);
        *(float4*)(pooled + (size_t)g * DIM + t * 4) = r;
    }
}

// ---------------- K4: out[g][o] = b_out[o] + sum_d pooled[g][d] * W_out[o][d]
__global__ __launch_bounds__(256) void k_out(const float* __restrict__ pooled,
                                             const float* __restrict__ WtOut,  // [d][o]
                                             const float* __restrict__ b_out,
                                             float* __restrict__ out) {
    int g = blockIdx.x;
    int t = threadIdx.x;
    __shared__ float p[256];
    p[t] = pooled[g * DIM + t];
    __syncthreads();
    float acc = b_out[t];
#pragma unroll 4
    for (int d = 0; d < DIM; d++) acc += p[d] * WtOut[d * DIM + t];
    out[g * DIM + t] = acc;
}

extern "C" void kernel_launch(void* const* d_in, const int* in_sizes, int n_in,
                              void* d_out, int out_size, void* d_ws, size_t ws_size,
                              hipStream_t stream) {
    (void)in_sizes; (void)n_in; (void)out_size; (void)ws_size;
    const float* x     = (const float*)d_in[0];
    const int*   batch = (const int*)d_in[1];
    const float* W_att = (const float*)d_in[2];
    const float* b_att = (const float*)d_in[3];
    const float* ctx   = (const float*)d_in[4];
    const float* W_out = (const float*)d_in[5];
    const float* b_out = (const float*)d_in[6];
    float* out = (float*)d_out;

    // workspace layout (floats), all written before read each launch
    float* scores = (float*)d_ws;            // 500000 (rounded 500032)
    float* w      = scores + 500032;         // 500000 (rounded 500032)
    float* pooled = w + 500032;              // 131072
    float* Wt_att = pooled + 131072;         // 16384
    float* Wt_out = Wt_att + 16384;          // 65536
    int*   seg_start = (int*)(Wt_out + 65536); // 513

    k_prep<<<dim3((DIM * DIM + 255) / 256), dim3(256), 0, stream>>>(W_att, W_out, Wt_att, Wt_out);
    k_offsets<<<dim3((N_NODES + 255) / 256), dim3(256), 0, stream>>>(batch, seg_start);
    k_scores<<<dim3((N_NODES + 255) / 256), dim3(256), 0, stream>>>(x, Wt_att, b_att, ctx, scores);
    k_segsoftmax<<<dim3(NG), dim3(256), 0, stream>>>(scores, seg_start, w);
    k_pool<<<dim3(NG), dim3(256), 0, stream>>>(x, w, seg_start, pooled);
    k_out<<<dim3(NG), dim3(256), 0, stream>>>(pooled, Wt_out, b_out, out);
}

// Round 2
// 799.523 us; speedup vs baseline: 1.3102x; 1.3102x over previous
//
#include <hip/hip_runtime.h>
#include <hip/hip_bf16.h>
#include <math.h>

#define N_NODES 500000
#define DIM 256
#define ADIM 64
#define NG 512
#define PSPLIT 4

typedef __attribute__((ext_vector_type(8))) short short8;
typedef __attribute__((ext_vector_type(4))) short short4v;
typedef __attribute__((ext_vector_type(4))) float floatx4;

__device__ inline unsigned short f2bf(float f) {
    union { float f; unsigned int u; } v; v.f = f;
    unsigned int u = v.u;
    unsigned int r = u + 0x7FFFu + ((u >> 16) & 1u);   // RNE
    return (unsigned short)(r >> 16);
}

// ---------------- prep: transpose W_out -> Wt_out[d][o]
__global__ __launch_bounds__(256) void k_prep(const float* __restrict__ W_out,
                                              float* __restrict__ Wt_out) {
    int idx = blockIdx.x * 256 + threadIdx.x;
    if (idx < DIM * DIM) {
        int o = idx / DIM, d = idx % DIM;
        Wt_out[d * DIM + o] = W_out[idx];
    }
}

// ---------------- segment offsets from sorted batch ids
__global__ __launch_bounds__(256) void k_offsets(const int* __restrict__ batch,
                                                 int* __restrict__ seg_start) {
    int i = blockIdx.x * 256 + threadIdx.x;
    if (i >= N_NODES) return;
    int b = batch[i];
    if (i == 0) {
        for (int g = 0; g <= b; g++) seg_start[g] = 0;
    } else {
        int pb = batch[i - 1];
        if (pb != b) {
            for (int g = pb + 1; g <= b; g++) seg_start[g] = i;
        }
    }
    if (i == N_NODES - 1) {
        for (int g = b + 1; g <= NG; g++) seg_start[g] = N_NODES;
    }
}

// ---------------- K1: scores via bf16 MFMA
// Block = 256 threads (4 waves), 64 nodes/block. Wave w computes attn cols
// [16w,16w+16) for all 64 nodes: 4 M-tiles x 1 N-tile of 16x16x32 MFMA.
// B-frags (W_att) held in 32 VGPRs for the whole K-loop; x staged fp32->bf16
// into LDS (stride 40 bf16 -> 2-way bank aliasing only, free).
__global__ __launch_bounds__(256) void k_scores(const float* __restrict__ x,
                                                const float* __restrict__ W_att,  // [64][256]
                                                const float* __restrict__ b_att,
                                                const float* __restrict__ ctx,
                                                float* __restrict__ scores) {
    __shared__ __align__(16) unsigned short xs[64 * 40];
    __shared__ float sacc[4][64];

    const int t = threadIdx.x;
    const int wave = t >> 6;
    const int lane = t & 63;
    const int quad = lane >> 4;     // 0..3
    const int lcol = lane & 15;     // 0..15
    const int base = blockIdx.x * 64;

    // --- B fragments: lane holds W_att[16*wave+lcol][quad*8 + j + 32*s], j=0..7
    short8 bfrag[8];
    {
        const float* wr = W_att + (size_t)(16 * wave + lcol) * DIM + quad * 8;
#pragma unroll
        for (int s = 0; s < 8; s++) {
            float4 f0 = *(const float4*)(wr + s * 32);
            float4 f1 = *(const float4*)(wr + s * 32 + 4);
            short8 b;
            b[0] = (short)f2bf(f0.x); b[1] = (short)f2bf(f0.y);
            b[2] = (short)f2bf(f0.z); b[3] = (short)f2bf(f0.w);
            b[4] = (short)f2bf(f1.x); b[5] = (short)f2bf(f1.y);
            b[6] = (short)f2bf(f1.z); b[7] = (short)f2bf(f1.w);
            bfrag[s] = b;
        }
    }

    // --- staging map: thread t -> row = t>>2, 64B-contiguous groups of 4 lanes
    const int srow = t >> 2;
    const int sk = (t & 3) * 4;          // float offset within 32-k chunk (first half)
    const int node_s = base + srow;
    const bool valid = node_s < N_NODES;
    const float* xrow = x + (size_t)node_s * DIM;

    floatx4 acc[4];
#pragma unroll
    for (int mt = 0; mt < 4; mt++) acc[mt] = (floatx4)0.f;

    float4 p0, p1;
    p0 = make_float4(0.f, 0.f, 0.f, 0.f); p1 = p0;
    if (valid) {
        p0 = *(const float4*)(xrow + sk);
        p1 = *(const float4*)(xrow + sk + 16);
    }

    for (int s = 0; s < 8; s++) {
        // cvt + LDS write (two 8B writes: k = sk..sk+4 and sk+16..sk+20)
        short4v w0, w1;
        w0[0] = (short)f2bf(p0.x); w0[1] = (short)f2bf(p0.y);
        w0[2] = (short)f2bf(p0.z); w0[3] = (short)f2bf(p0.w);
        w1[0] = (short)f2bf(p1.x); w1[1] = (short)f2bf(p1.y);
        w1[2] = (short)f2bf(p1.z); w1[3] = (short)f2bf(p1.w);
        *(short4v*)(xs + srow * 40 + sk) = w0;
        *(short4v*)(xs + srow * 40 + sk + 16) = w1;

        // prefetch next chunk while this one is consumed
        float4 n0 = make_float4(0.f, 0.f, 0.f, 0.f), n1 = n0;
        if (s < 7 && valid) {
            n0 = *(const float4*)(xrow + (s + 1) * 32 + sk);
            n1 = *(const float4*)(xrow + (s + 1) * 32 + sk + 16);
        }
        __syncthreads();

#pragma unroll
        for (int mt = 0; mt < 4; mt++) {
            short8 afrag = *(const short8*)(xs + (mt * 16 + lcol) * 40 + quad * 8);
            acc[mt] = __builtin_amdgcn_mfma_f32_16x16x32_bf16(afrag, bfrag[s], acc[mt], 0, 0, 0);
        }
        __syncthreads();
        p0 = n0; p1 = n1;
    }

    // --- epilogue: scores[node] = sum_col ctx[col]*tanh(logit + b_att[col])
    const float ctxv = ctx[16 * wave + lcol];
    const float bv = b_att[16 * wave + lcol];
    float partial[4][4];
#pragma unroll
    for (int mt = 0; mt < 4; mt++) {
#pragma unroll
        for (int r = 0; r < 4; r++) {
            float v = ctxv * tanhf(acc[mt][r] + bv);
            v += __shfl_xor(v, 1);
            v += __shfl_xor(v, 2);
            v += __shfl_xor(v, 4);
            v += __shfl_xor(v, 8);
            partial[mt][r] = v;   // valid on all lanes; cols of this wave summed
        }
    }
    if (lcol == 0) {
#pragma unroll
        for (int mt = 0; mt < 4; mt++)
#pragma unroll
            for (int r = 0; r < 4; r++)
                sacc[wave][mt * 16 + quad * 4 + r] = partial[mt][r];
    }
    __syncthreads();
    if (t < 64) {
        float sres = (sacc[0][t] + sacc[1][t]) + (sacc[2][t] + sacc[3][t]);
        int node = base + t;
        if (node < N_NODES) scores[node] = sres;
    }
}

// ---------------- K2: per-segment stable softmax, w written in-place into scores
__global__ __launch_bounds__(256) void k_segsoftmax(float* __restrict__ scores,
                                                    const int* __restrict__ seg_start) {
    int g = blockIdx.x;
    int s0 = seg_start[g], s1 = seg_start[g + 1];
    int t = threadIdx.x;
    __shared__ float red[256];

    float m = -INFINITY;
    for (int i = s0 + t; i < s1; i += 256) m = fmaxf(m, scores[i]);
    red[t] = m;
    __syncthreads();
    for (int off = 128; off > 0; off >>= 1) {
        if (t < off) red[t] = fmaxf(red[t], red[t + off]);
        __syncthreads();
    }
    m = red[0];
    __syncthreads();

    float sum = 0.f;
    for (int i = s0 + t; i < s1; i += 256) sum += __expf(scores[i] - m);
    red[t] = sum;
    __syncthreads();
    for (int off = 128; off > 0; off >>= 1) {
        if (t < off) red[t] += red[t + off];
        __syncthreads();
    }
    float inv = 1.f / (red[0] + 1e-8f);
    __syncthreads();

    for (int i = s0 + t; i < s1; i += 256) scores[i] = __expf(scores[i] - m) * inv;
}

// ---------------- K3: weighted pooling, segment split PSPLIT ways
__global__ __launch_bounds__(256) void k_pool(const float* __restrict__ x,
                                              const float* __restrict__ w,   // = scores (in-place)
                                              const int* __restrict__ seg_start,
                                              float* __restrict__ partial) {
    int g = blockIdx.x / PSPLIT, sp = blockIdx.x % PSPLIT;
    int s0 = seg_start[g], s1 = seg_start[g + 1];
    int len = s1 - s0;
    int chunk = (len + PSPLIT - 1) / PSPLIT;
    int c0 = s0 + sp * chunk;
    int c1 = min(s1, c0 + chunk);

    int t = threadIdx.x;
    int c = (t & 63) * 4;
    int grp = t >> 6;

    float4 acc = make_float4(0.f, 0.f, 0.f, 0.f);
    for (int i = c0 + grp; i < c1; i += 4) {
        float wi = w[i];
        float4 v = *(const float4*)(x + (size_t)i * DIM + c);
        acc.x += wi * v.x;
        acc.y += wi * v.y;
        acc.z += wi * v.z;
        acc.w += wi * v.w;
    }

    __shared__ float4 red[4][64];
    red[grp][t & 63] = acc;
    __syncthreads();
    if (t < 64) {
        float4 r0 = red[0][t], r1 = red[1][t], r2 = red[2][t], r3 = red[3][t];
        float4 r;
        r.x = (r0.x + r1.x) + (r2.x + r3.x);
        r.y = (r0.y + r1.y) + (r2.y + r3.y);
        r.z = (r0.z + r1.z) + (r2.z + r3.z);
        r.w = (r0.w + r1.w) + (r2.w + r3.w);
        *(float4*)(partial + (size_t)blockIdx.x * DIM + t * 4) = r;
    }
}

__global__ __launch_bounds__(256) void k_pool_reduce(const float* __restrict__ partial,
                                                     float* __restrict__ pooled) {
    int g = blockIdx.x;
    int t = threadIdx.x;
    float s = 0.f;
#pragma unroll
    for (int sp = 0; sp < PSPLIT; sp++)
        s += partial[(size_t)(g * PSPLIT + sp) * DIM + t];
    pooled[(size_t)g * DIM + t] = s;
}

// ---------------- K4: out = pooled @ W_out^T + b_out
__global__ __launch_bounds__(256) void k_out(const float* __restrict__ pooled,
                                             const float* __restrict__ WtOut,  // [d][o]
                                             const float* __restrict__ b_out,
                                             float* __restrict__ out) {
    int g = blockIdx.x;
    int t = threadIdx.x;
    __shared__ float p[256];
    p[t] = pooled[g * DIM + t];
    __syncthreads();
    float acc = b_out[t];
#pragma unroll 4
    for (int d = 0; d < DIM; d++) acc += p[d] * WtOut[d * DIM + t];
    out[g * DIM + t] = acc;
}

extern "C" void kernel_launch(void* const* d_in, const int* in_sizes, int n_in,
                              void* d_out, int out_size, void* d_ws, size_t ws_size,
                              hipStream_t stream) {
    (void)in_sizes; (void)n_in; (void)out_size; (void)ws_size;
    const float* x     = (const float*)d_in[0];
    const int*   batch = (const int*)d_in[1];
    const float* W_att = (const float*)d_in[2];
    const float* b_att = (const float*)d_in[3];
    const float* ctx   = (const float*)d_in[4];
    const float* W_out = (const float*)d_in[5];
    const float* b_out = (const float*)d_in[6];
    float* out = (float*)d_out;

    // workspace layout (floats); total ~4.9 MB
    float* scores  = (float*)d_ws;                 // 500032 (doubles as w)
    float* partial = scores + 500032;              // 512*4*256 = 524288
    float* pooled  = partial + 524288;             // 131072
    float* Wt_out  = pooled + 131072;              // 65536
    int*   seg_start = (int*)(Wt_out + 65536);     // 513

    k_prep<<<dim3(DIM), dim3(256), 0, stream>>>(W_out, Wt_out);
    k_offsets<<<dim3((N_NODES + 255) / 256), dim3(256), 0, stream>>>(batch, seg_start);
    k_scores<<<dim3((N_NODES + 63) / 64), dim3(256), 0, stream>>>(x, W_att, b_att, ctx, scores);
    k_segsoftmax<<<dim3(NG), dim3(256), 0, stream>>>(scores, seg_start);
    k_pool<<<dim3(NG * PSPLIT), dim3(256), 0, stream>>>(x, scores, seg_start, partial);
    k_pool_reduce<<<dim3(NG), dim3(256), 0, stream>>>(partial, pooled);
    k_out<<<dim3(NG), dim3(256), 0, stream>>>(pooled, Wt_out, b_out, out);
}